// Round 1
// baseline (539.741 us; speedup 1.0000x reference)
//
#include <hip/hip_runtime.h>

// GaussianSmoothing3d: depthwise 3D conv, 3 channels, 5x5x5 separable Gaussian,
// SAME zero padding. Input/output fp32 (1,3,256,256,256).
//
// Strategy: recover 1D factors (kz,ky,kx) from the 125-tap 3D kernel via
// marginal sums (kernel is outer(k,k,k)/sum -> exact). Fused separable conv:
// per block, slide along z one input slice at a time:
//   LDS raw slice (TY+4)x(TX+4) -> x-conv -> LDS xb (TY+4)xTX (float4/thread)
//   -> y-conv in registers -> 5-deep z shift-register accumulators
//   -> one coalesced float4 output plane store per slice.

#define N   256
#define KS  5
#define R   2
#define TX  64
#define TY  16
#define TZ  32
#define NT  256

__global__ __launch_bounds__(NT) void gauss3d_kernel(
    const float* __restrict__ xin,
    const float* __restrict__ wxp,
    const float* __restrict__ wyp,
    const float* __restrict__ wzp,
    float* __restrict__ out)
{
    __shared__ float raw[(TY + 4) * (TX + 4)];   // padded input slice
    __shared__ float xb[(TY + 4) * TX];          // after x-conv
    __shared__ float k1[3][KS];                  // [0]=kz(d) [1]=ky(h) [2]=kx(w)

    const int tid = threadIdx.x;
    const int c   = blockIdx.z / (N / TZ);
    const int zt  = blockIdx.z % (N / TZ);
    const int x0  = blockIdx.x * TX;
    const int y0  = blockIdx.y * TY;
    const int z0  = zt * TZ;

    const float* w = (c == 0) ? wxp : (c == 1) ? wyp : wzp;

    // Extract 1D factors: marginal sums over the other two axes.
    if (tid < 3 * KS) {
        const int axis = tid / KS, idx = tid % KS;
        float s = 0.f;
        for (int a = 0; a < KS; ++a)
            for (int b = 0; b < KS; ++b) {
                int off;
                if (axis == 0)      off = idx * 25 + a * 5 + b;   // kz: sum over h,w
                else if (axis == 1) off = a * 25 + idx * 5 + b;   // ky: sum over d,w
                else                off = a * 25 + b * 5 + idx;   // kx: sum over d,h
                s += w[off];
            }
        k1[axis][idx] = s;
    }
    __syncthreads();

    float kzr[KS], kyr[KS], kxr[KS];
#pragma unroll
    for (int i = 0; i < KS; ++i) {
        kzr[i] = k1[0][i];
        kyr[i] = k1[1][i];
        kxr[i] = k1[2][i];
    }

    // This thread's output xy-point: a float4 run along x.
    const int iy = tid / (TX / 4);            // 0..15
    const int ix = (tid % (TX / 4)) * 4;      // 0,4,...,60

    float4 acc[KS];  // acc[j] is partial sum for output plane zo = zs - R + j
#pragma unroll
    for (int j = 0; j < KS; ++j) acc[j] = make_float4(0.f, 0.f, 0.f, 0.f);

    const float* xc = xin + (size_t)c * N * N * N;
    float*       oc = out + (size_t)c * N * N * N;

    for (int zs = z0 - R; zs < z0 + TZ + R; ++zs) {
        __syncthreads();   // protect xb (read last iter) before rewrite, raw before reload
        // ---- stage padded input slice ----
        const bool zin = (zs >= 0) && (zs < N);
        for (int i = tid; i < (TY + 4) * (TX + 4); i += NT) {
            const int r   = i / (TX + 4);
            const int cix = i - r * (TX + 4);
            const int gy  = y0 + r - R;
            const int gx  = x0 + cix - R;
            float v = 0.f;
            if (zin && (unsigned)gy < (unsigned)N && (unsigned)gx < (unsigned)N)
                v = xc[((size_t)zs * N + gy) * N + gx];
            raw[i] = v;
        }
        __syncthreads();
        // ---- x-conv: (TY+4) x TX points, float4 per iteration ----
        for (int i = tid; i < (TY + 4) * (TX / 4); i += NT) {
            const int r  = i / (TX / 4);
            const int x4 = (i - r * (TX / 4)) * 4;
            const float* rp = &raw[r * (TX + 4) + x4];
            const float a0 = rp[0], a1 = rp[1], a2 = rp[2], a3 = rp[3];
            const float a4 = rp[4], a5 = rp[5], a6 = rp[6], a7 = rp[7];
            float4 o;
            o.x = kxr[0]*a0 + kxr[1]*a1 + kxr[2]*a2 + kxr[3]*a3 + kxr[4]*a4;
            o.y = kxr[0]*a1 + kxr[1]*a2 + kxr[2]*a3 + kxr[3]*a4 + kxr[4]*a5;
            o.z = kxr[0]*a2 + kxr[1]*a3 + kxr[2]*a4 + kxr[3]*a5 + kxr[4]*a6;
            o.w = kxr[0]*a3 + kxr[1]*a4 + kxr[2]*a5 + kxr[3]*a6 + kxr[4]*a7;
            *(float4*)&xb[r * TX + x4] = o;
        }
        __syncthreads();
        // ---- y-conv (registers) ----
        float4 s = make_float4(0.f, 0.f, 0.f, 0.f);
#pragma unroll
        for (int h = 0; h < KS; ++h) {
            const float4 v = *(const float4*)&xb[(iy + h) * TX + ix];
            const float kh = kyr[h];
            s.x += kh * v.x; s.y += kh * v.y; s.z += kh * v.z; s.w += kh * v.w;
        }
        // ---- z accumulate: acc[j] (zo = zs-R+j) gets weight kz[2R - j] = kz[4-j] ----
#pragma unroll
        for (int j = 0; j < KS; ++j) {
            const float kj = kzr[4 - j];
            acc[j].x += kj * s.x; acc[j].y += kj * s.y;
            acc[j].z += kj * s.z; acc[j].w += kj * s.w;
        }
        // ---- retire plane zo = zs - R ----
        const int zo = zs - R;
        if (zo >= z0) {
            *(float4*)&oc[((size_t)zo * N + (y0 + iy)) * N + (x0 + ix)] = acc[0];
        }
        // shift register
        acc[0] = acc[1]; acc[1] = acc[2]; acc[2] = acc[3]; acc[3] = acc[4];
        acc[4] = make_float4(0.f, 0.f, 0.f, 0.f);
    }
}

extern "C" void kernel_launch(void* const* d_in, const int* in_sizes, int n_in,
                              void* d_out, int out_size, void* d_ws, size_t ws_size,
                              hipStream_t stream) {
    const float* x  = (const float*)d_in[0];
    const float* wx = (const float*)d_in[1];
    const float* wy = (const float*)d_in[2];
    const float* wz = (const float*)d_in[3];
    float* o = (float*)d_out;

    dim3 grid(N / TX, N / TY, 3 * (N / TZ));   // 4 x 16 x 24
    dim3 block(NT);
    gauss3d_kernel<<<grid, block, 0, stream>>>(x, wx, wy, wz, o);
}

// Round 2
// 372.942 us; speedup vs baseline: 1.4472x; 1.4472x over previous
//
#include <hip/hip_runtime.h>

// GaussianSmoothing3d: depthwise 3D conv, 3 ch, 5x5x5 separable Gaussian, SAME
// zero pad, fp32 (1,3,256,256,256).
//
// R2 restructure (was barrier/latency-bound at 313us, both pipes <18%):
//  - ZB=4 z-slices staged per round: 9 rounds x 2 barriers (was 36 x 3).
//  - Staging split into load-phase (11 independent float2 loads into regs)
//    then write-phase -> full memory-level parallelism.
//  - No intermediate x-conv LDS buffer: each thread reads 2 aligned
//    ds_read_b128 per row and does x-conv + y-conv in registers.
//  - z handled by 5-deep register shift accumulators; one coalesced float4
//    output plane store per slice.

#define N    256
#define KS   5
#define R    2
#define TX   64
#define TY   16
#define TZ   32
#define ZB   4
#define NT   256
#define LROW 68                      // floats per staged row (no pad; 272B = 16B-aligned stride)
#define ROWS (TY + 4)                // 20
#define UPR  34                      // float2 units per row
#define UNITS (ZB * ROWS * UPR)      // 2720
#define MAXU ((UNITS + NT - 1) / NT) // 11

__global__ __launch_bounds__(NT) void gauss3d_kernel(
    const float* __restrict__ xin,
    const float* __restrict__ wxp,
    const float* __restrict__ wyp,
    const float* __restrict__ wzp,
    float* __restrict__ out)
{
    __shared__ float raw[ZB][ROWS][LROW];   // 21760 B; pos p of a row holds input col (p-2)
    __shared__ float k1[3][KS];             // [0]=kz [1]=ky [2]=kx

    const int tid = threadIdx.x;
    const int c   = blockIdx.z / (N / TZ);
    const int zt  = blockIdx.z % (N / TZ);
    const int x0  = blockIdx.x * TX;
    const int y0  = blockIdx.y * TY;
    const int z0  = zt * TZ;

    const float* w = (c == 0) ? wxp : (c == 1) ? wyp : wzp;

    // Recover 1D factors via marginal sums (kernel is outer(k,k,k)/sum).
    if (tid < 3 * KS) {
        const int axis = tid / KS, idx = tid % KS;
        float s = 0.f;
        for (int a = 0; a < KS; ++a)
            for (int b = 0; b < KS; ++b) {
                int off;
                if (axis == 0)      off = idx * 25 + a * 5 + b;
                else if (axis == 1) off = a * 25 + idx * 5 + b;
                else                off = a * 25 + b * 5 + idx;
                s += w[off];
            }
        k1[axis][idx] = s;
    }
    __syncthreads();

    float kzr[KS], kyr[KS], kxr[KS];
#pragma unroll
    for (int i = 0; i < KS; ++i) {
        kzr[i] = k1[0][i];
        kyr[i] = k1[1][i];
        kxr[i] = k1[2][i];
    }

    const int iy = tid >> 4;          // 0..15
    const int ix = (tid & 15) << 2;   // 0,4,...,60

    float4 acc[KS];  // acc[j]: partial for output plane zo = (current zs) - R + j
#pragma unroll
    for (int j = 0; j < KS; ++j) acc[j] = make_float4(0.f, 0.f, 0.f, 0.f);

    const float* xc = xin + (size_t)c * N * N * N;
    float*       oc = out + (size_t)c * N * N * N;

    float* rawf = (float*)raw;

    for (int rnd = 0; rnd < (TZ + 2 * R) / ZB; ++rnd) {   // 9 rounds
        const int zb = z0 - R + rnd * ZB;                 // first slice this round

        __syncthreads();   // protect raw: prior round's readers done

        // ---- phase 1: issue all global loads (independent -> deep MLP) ----
        float2 v[MAXU];
#pragma unroll
        for (int i = 0; i < MAXU; ++i) {
            v[i] = make_float2(0.f, 0.f);
            const int u = tid + i * NT;
            if (u < UNITS) {
                const int rowi = u / UPR;            // 0..79
                const int j    = u - rowi * UPR;     // 0..33
                const int s    = rowi / ROWS;        // 0..3
                const int r    = rowi - s * ROWS;    // 0..19
                const int zs = zb + s;
                const int gy = y0 + r - R;
                const int gx = x0 - R + 2 * j;       // even; pair never straddles 0/256
                if ((unsigned)zs < (unsigned)N && (unsigned)gy < (unsigned)N &&
                    (unsigned)gx < (unsigned)N)
                    v[i] = *(const float2*)&xc[((size_t)zs * N + gy) * N + gx];
            }
        }
        // ---- phase 2: LDS writes (unit u -> float offset 2u, 8B aligned) ----
#pragma unroll
        for (int i = 0; i < MAXU; ++i) {
            const int u = tid + i * NT;
            if (u < UNITS)
                *(float2*)&rawf[2 * u] = v[i];
        }
        __syncthreads();

        // ---- compute ZB slices from LDS ----
#pragma unroll
        for (int s = 0; s < ZB; ++s) {
            float4 yv = make_float4(0.f, 0.f, 0.f, 0.f);
#pragma unroll
            for (int h = 0; h < KS; ++h) {
                const float* rp = &raw[s][iy + h][ix];   // 16B aligned
                const float4 a = *(const float4*)rp;
                const float4 b = *(const float4*)(rp + 4);
                // x-conv: pos ix..ix+7 hold input cols ix-2..ix+5
                const float o0 = kxr[0]*a.x + kxr[1]*a.y + kxr[2]*a.z + kxr[3]*a.w + kxr[4]*b.x;
                const float o1 = kxr[0]*a.y + kxr[1]*a.z + kxr[2]*a.w + kxr[3]*b.x + kxr[4]*b.y;
                const float o2 = kxr[0]*a.z + kxr[1]*a.w + kxr[2]*b.x + kxr[3]*b.y + kxr[4]*b.z;
                const float o3 = kxr[0]*a.w + kxr[1]*b.x + kxr[2]*b.y + kxr[3]*b.z + kxr[4]*b.w;
                const float kh = kyr[h];
                yv.x += kh * o0; yv.y += kh * o1; yv.z += kh * o2; yv.w += kh * o3;
            }
            // z accumulate: acc[j] (zo = zs-R+j) gets weight kz[4-j]
#pragma unroll
            for (int j = 0; j < KS; ++j) {
                const float kj = kzr[4 - j];
                acc[j].x += kj * yv.x; acc[j].y += kj * yv.y;
                acc[j].z += kj * yv.z; acc[j].w += kj * yv.w;
            }
            // retire plane zo = zs - R (complete after this slice)
            const int zo = zb + s - R;
            if (zo >= z0) {
                *(float4*)&oc[((size_t)zo * N + (y0 + iy)) * N + (x0 + ix)] = acc[0];
            }
            acc[0] = acc[1]; acc[1] = acc[2]; acc[2] = acc[3]; acc[3] = acc[4];
            acc[4] = make_float4(0.f, 0.f, 0.f, 0.f);
        }
    }
}

extern "C" void kernel_launch(void* const* d_in, const int* in_sizes, int n_in,
                              void* d_out, int out_size, void* d_ws, size_t ws_size,
                              hipStream_t stream) {
    const float* x  = (const float*)d_in[0];
    const float* wx = (const float*)d_in[1];
    const float* wy = (const float*)d_in[2];
    const float* wz = (const float*)d_in[3];
    float* o = (float*)d_out;

    dim3 grid(N / TX, N / TY, 3 * (N / TZ));   // 4 x 16 x 24 = 1536 blocks
    dim3 block(NT);
    gauss3d_kernel<<<grid, block, 0, stream>>>(x, wx, wy, wz, o);
}